// Round 12
// baseline (109.177 us; speedup 1.0000x reference)
//
#include <hip/hip_runtime.h>

// Diagonal RNN scan: h_t = a_p * h_{t-1} + x_t,  a_p = 1 - relu(w_p), h_{-1}=0.
// x (B=32, L=8192, P=128) fp32, w (P,) fp32, out (B,L,P) fp32.
// R12: single-pass depth-1 lookback with INVALIDATE-FREE waiting.
//  R6/R8/R10 died because ACQUIRE-in-spin emits a cache invalidate per poll,
//  poisoning co-resident streaming waves. Here: relaxed spin + one acquire
//  fence per block; agg published via relaxed atomic (coherence-point) ops.

typedef float f4 __attribute__((ext_vector_type(4)));

#define BB 32
#define LL 8192
#define PP 128
#define TPB 256
#define GPB 8                    // 32-lane groups per block
#define CHUNK 32                 // steps per group
#define BSTEPS (GPB * CHUNK)     // 256 steps per block
#define BPR (LL / BSTEPS)        // 32 segments per row
#define GRID (BB * BPR)          // 1024 blocks -> 4/CU, all co-resident

__global__ __launch_bounds__(TPB) void k_scan(
    const float* __restrict__ x, const float* __restrict__ w,
    float* __restrict__ agg /* [BB][BPR][PP] */,
    int* __restrict__ flags /* [BB*BPR] */,
    float* __restrict__ out) {
  const int tid = threadIdx.x;
  const int g = tid >> 5;
  const int l = tid & 31;
  const int b = blockIdx.x / BPR;
  const int s = blockIdx.x % BPR;

  const f4 w4 = reinterpret_cast<const f4*>(w)[l];
  f4 a4;
  a4.x = 1.0f - fmaxf(w4.x, 0.0f);
  a4.y = 1.0f - fmaxf(w4.y, 0.0f);
  a4.z = 1.0f - fmaxf(w4.z, 0.0f);
  a4.w = 1.0f - fmaxf(w4.w, 0.0f);

  const size_t off =
      ((size_t)b * LL + (size_t)s * BSTEPS + (size_t)g * CHUNK) * (PP / 4) + l;
  const f4* xv = reinterpret_cast<const f4*>(x) + off;

  __shared__ float sf[GPB][PP];
  __shared__ float sseed[GPB][PP];

  // ---- Phase 1: stream-scan (cacheable -> fills L3), group finals to LDS.
  {
    f4 h = (f4)(0.0f);
#pragma unroll 8
    for (int t = 0; t < CHUNK; ++t) {
      const f4 v = xv[(size_t)t * (PP / 4)];
      h.x = fmaf(a4.x, h.x, v.x);
      h.y = fmaf(a4.y, h.y, v.y);
      h.z = fmaf(a4.z, h.z, v.z);
      h.w = fmaf(a4.w, h.w, v.w);
    }
    reinterpret_cast<f4*>(&sf[g][0])[l] = h;
  }
  __syncthreads();

  // ---- Publish block aggregate (coherence-point stores), then flag.
  if (tid < PP) {
    const int p = tid;
    const float a = 1.0f - fmaxf(w[p], 0.0f);
    float a32 = a;
#pragma unroll
    for (int i = 0; i < 5; ++i) a32 *= a32;  // a^32
    float bf = 0.f;
#pragma unroll
    for (int g2 = 0; g2 < GPB; ++g2) bf = fmaf(a32, bf, sf[g2][p]);
    __hip_atomic_store(&agg[((size_t)b * BPR + s) * PP + p], bf,
                       __ATOMIC_RELAXED, __HIP_MEMORY_SCOPE_AGENT);
  }
  __syncthreads();
  if (tid == 0 && s < BPR - 1) {
    __builtin_amdgcn_fence(__ATOMIC_RELEASE, "agent");  // one writeback
    __hip_atomic_store(&flags[b * BPR + s], 1, __ATOMIC_RELAXED,
                       __HIP_MEMORY_SCOPE_AGENT);
  }

  // ---- Wait: relaxed sweeps (NO invalidate), one acquire fence at the end.
  if (s > 0) {
    if (tid == 0) {
      const int* fl = flags + b * BPR;
      int nseen;
      do {
        nseen = 0;
        for (int j = 0; j < s; ++j)
          nseen += __hip_atomic_load(&fl[j], __ATOMIC_RELAXED,
                                     __HIP_MEMORY_SCOPE_AGENT);
        if (nseen < s) __builtin_amdgcn_s_sleep(32);
      } while (nseen < s);
      __builtin_amdgcn_fence(__ATOMIC_ACQUIRE, "agent");  // once per block
    }
    __syncthreads();
  }

  // ---- Lookback (relaxed atomic reads: coherence-point, never stale).
  if (tid < PP) {
    const int p = tid;
    const float a = 1.0f - fmaxf(w[p], 0.0f);
    float a32 = a;
#pragma unroll
    for (int i = 0; i < 5; ++i) a32 *= a32;  // a^32
    float aB = a32;
#pragma unroll
    for (int i = 0; i < 3; ++i) aB *= aB;    // a^256

    float hh = 0.f;
    const float* bp = agg + (size_t)b * BPR * PP + p;
    int j = 0;
    for (; j + 4 <= s; j += 4) {
      const float v0 = __hip_atomic_load(&bp[(size_t)(j + 0) * PP],
                                         __ATOMIC_RELAXED, __HIP_MEMORY_SCOPE_AGENT);
      const float v1 = __hip_atomic_load(&bp[(size_t)(j + 1) * PP],
                                         __ATOMIC_RELAXED, __HIP_MEMORY_SCOPE_AGENT);
      const float v2 = __hip_atomic_load(&bp[(size_t)(j + 2) * PP],
                                         __ATOMIC_RELAXED, __HIP_MEMORY_SCOPE_AGENT);
      const float v3 = __hip_atomic_load(&bp[(size_t)(j + 3) * PP],
                                         __ATOMIC_RELAXED, __HIP_MEMORY_SCOPE_AGENT);
      hh = fmaf(aB, hh, v0);
      hh = fmaf(aB, hh, v1);
      hh = fmaf(aB, hh, v2);
      hh = fmaf(aB, hh, v3);
    }
    for (; j < s; ++j)
      hh = fmaf(aB, hh, __hip_atomic_load(&bp[(size_t)j * PP], __ATOMIC_RELAXED,
                                          __HIP_MEMORY_SCOPE_AGENT));

#pragma unroll
    for (int g2 = 0; g2 < GPB; ++g2) {
      sseed[g2][p] = hh;
      hh = fmaf(a32, hh, sf[g2][p]);
    }
  }
  __syncthreads();

  // ---- Phase 3: seeded re-scan (x from L3, nt), nt emit.
  f4 h = reinterpret_cast<const f4*>(&sseed[g][0])[l];
  f4* ov = reinterpret_cast<f4*>(out) + off;
#pragma unroll 8
  for (int t = 0; t < CHUNK; ++t) {
    const f4 v = __builtin_nontemporal_load(&xv[(size_t)t * (PP / 4)]);
    h.x = fmaf(a4.x, h.x, v.x);
    h.y = fmaf(a4.y, h.y, v.y);
    h.z = fmaf(a4.z, h.z, v.z);
    h.w = fmaf(a4.w, h.w, v.w);
    __builtin_nontemporal_store(h, &ov[(size_t)t * (PP / 4)]);
  }
}

extern "C" void kernel_launch(void* const* d_in, const int* in_sizes, int n_in,
                              void* d_out, int out_size, void* d_ws, size_t ws_size,
                              hipStream_t stream) {
  const float* x = (const float*)d_in[0];
  const float* w = (const float*)d_in[1];
  float* out = (float*)d_out;
  int* flags = (int*)d_ws;                      // 4 KiB
  float* agg = (float*)((char*)d_ws + 65536);   // 512 KiB

  hipMemsetAsync(flags, 0, GRID * sizeof(int), stream);
  k_scan<<<GRID, TPB, 0, stream>>>(x, w, agg, flags, out);
}

// Round 13
// 78.012 us; speedup vs baseline: 1.3995x; 1.3995x over previous
//
#include <hip/hip_runtime.h>
#include <math.h>

// Diagonal RNN scan: h_t = a_p * h_{t-1} + x_t,  a_p = 1 - relu(w_p), h_{-1}=0.
// x (B=32, L=8192, P=128) fp32, w (P,) fp32, out (B,L,P) fp32.
// R13: single-pass depth-1 lookback, ZERO-FENCE sync via NaN sentinels.
//  agg[] pre-memset to 0xFF (NaN). Producers: relaxed atomic stores of the
//  aggregate values (no release fence -> no buffer_wbl2). Consumers: relaxed
//  atomic loads of exactly the words they need, retrying while NaN (no
//  acquire fence -> no cache invalidate). Data IS the flag; the only
//  ordering needed is the data dependency itself.

typedef float f4 __attribute__((ext_vector_type(4)));

#define BB 32
#define LL 8192
#define PP 128
#define TPB 256
#define GPB 8                    // 32-lane groups per block
#define CHUNK 32                 // steps per group
#define BSTEPS (GPB * CHUNK)     // 256 steps per block
#define BPR (LL / BSTEPS)        // 32 segments per row
#define GRID (BB * BPR)          // 1024 blocks -> 4/CU, co-resident

__device__ __forceinline__ float poll_agg(const float* p) {
  float v = __hip_atomic_load(p, __ATOMIC_RELAXED, __HIP_MEMORY_SCOPE_AGENT);
  while (v != v) {  // NaN sentinel -> not yet published
    __builtin_amdgcn_s_sleep(8);
    v = __hip_atomic_load(p, __ATOMIC_RELAXED, __HIP_MEMORY_SCOPE_AGENT);
  }
  return v;
}

__global__ __launch_bounds__(TPB) void k_scan(
    const float* __restrict__ x, const float* __restrict__ w,
    float* __restrict__ agg /* [BB][BPR][PP], NaN-initialized */,
    float* __restrict__ out) {
  const int tid = threadIdx.x;
  const int g = tid >> 5;
  const int l = tid & 31;
  const int b = blockIdx.x / BPR;
  const int s = blockIdx.x % BPR;  // same-row blocks adjacent in dispatch

  const f4 w4 = reinterpret_cast<const f4*>(w)[l];
  f4 a4;
  a4.x = 1.0f - fmaxf(w4.x, 0.0f);
  a4.y = 1.0f - fmaxf(w4.y, 0.0f);
  a4.z = 1.0f - fmaxf(w4.z, 0.0f);
  a4.w = 1.0f - fmaxf(w4.w, 0.0f);

  const size_t off =
      ((size_t)b * LL + (size_t)s * BSTEPS + (size_t)g * CHUNK) * (PP / 4) + l;
  const f4* xv = reinterpret_cast<const f4*>(x) + off;

  __shared__ float sf[GPB][PP];
  __shared__ float sseed[GPB][PP];

  // ---- Phase 1: stream-scan (cacheable -> fills L3), group finals to LDS.
  {
    f4 h = (f4)(0.0f);
#pragma unroll 8
    for (int t = 0; t < CHUNK; ++t) {
      const f4 v = xv[(size_t)t * (PP / 4)];
      h.x = fmaf(a4.x, h.x, v.x);
      h.y = fmaf(a4.y, h.y, v.y);
      h.z = fmaf(a4.z, h.z, v.z);
      h.w = fmaf(a4.w, h.w, v.w);
    }
    reinterpret_cast<f4*>(&sf[g][0])[l] = h;
  }
  __syncthreads();

  // ---- Publish block aggregate: the VALUE is the ready-signal (was NaN).
  if (tid < PP) {
    const int p = tid;
    const float a = 1.0f - fmaxf(w[p], 0.0f);
    float a32 = a;
#pragma unroll
    for (int i = 0; i < 5; ++i) a32 *= a32;  // a^32
    float bf = 0.f;
#pragma unroll
    for (int g2 = 0; g2 < GPB; ++g2) bf = fmaf(a32, bf, sf[g2][p]);
    __hip_atomic_store(&agg[((size_t)b * BPR + s) * PP + p], bf,
                       __ATOMIC_RELAXED, __HIP_MEMORY_SCOPE_AGENT);
  }

  // ---- Lookback: poll predecessor aggregates (own channel only), batched x4.
  if (tid < PP) {
    const int p = tid;
    const float a = 1.0f - fmaxf(w[p], 0.0f);
    float a32 = a;
#pragma unroll
    for (int i = 0; i < 5; ++i) a32 *= a32;  // a^32
    float aB = a32;
#pragma unroll
    for (int i = 0; i < 3; ++i) aB *= aB;    // a^256

    float hh = 0.f;
    const float* bp = agg + (size_t)b * BPR * PP + p;
    int j = 0;
    for (; j + 4 <= s; j += 4) {
      const float v0 = poll_agg(&bp[(size_t)(j + 0) * PP]);
      const float v1 = poll_agg(&bp[(size_t)(j + 1) * PP]);
      const float v2 = poll_agg(&bp[(size_t)(j + 2) * PP]);
      const float v3 = poll_agg(&bp[(size_t)(j + 3) * PP]);
      hh = fmaf(aB, hh, v0);
      hh = fmaf(aB, hh, v1);
      hh = fmaf(aB, hh, v2);
      hh = fmaf(aB, hh, v3);
    }
    for (; j < s; ++j) hh = fmaf(aB, hh, poll_agg(&bp[(size_t)j * PP]));

#pragma unroll
    for (int g2 = 0; g2 < GPB; ++g2) {
      sseed[g2][p] = hh;
      hh = fmaf(a32, hh, sf[g2][p]);
    }
  }
  __syncthreads();

  // ---- Phase 3: seeded re-scan (x from L3, nt), nt emit.
  f4 h = reinterpret_cast<const f4*>(&sseed[g][0])[l];
  f4* ov = reinterpret_cast<f4*>(out) + off;
#pragma unroll 8
  for (int t = 0; t < CHUNK; ++t) {
    const f4 v = __builtin_nontemporal_load(&xv[(size_t)t * (PP / 4)]);
    h.x = fmaf(a4.x, h.x, v.x);
    h.y = fmaf(a4.y, h.y, v.y);
    h.z = fmaf(a4.z, h.z, v.z);
    h.w = fmaf(a4.w, h.w, v.w);
    __builtin_nontemporal_store(h, &ov[(size_t)t * (PP / 4)]);
  }
}

extern "C" void kernel_launch(void* const* d_in, const int* in_sizes, int n_in,
                              void* d_out, int out_size, void* d_ws, size_t ws_size,
                              hipStream_t stream) {
  const float* x = (const float*)d_in[0];
  const float* w = (const float*)d_in[1];
  float* out = (float*)d_out;
  float* agg = (float*)d_ws;  // 512 KiB

  // 0xFF bytes -> agg[] = quiet NaN sentinels
  hipMemsetAsync(agg, 0xFF, (size_t)BB * BPR * PP * sizeof(float), stream);
  k_scan<<<GRID, TPB, 0, stream>>>(x, w, agg, out);
}